// Round 17
// baseline (609.076 us; speedup 1.0000x reference)
//
#include <hip/hip_runtime.h>
#include <math.h>

namespace {

typedef _Float16 f16;
typedef _Float16 f16x8 __attribute__((ext_vector_type(8)));
typedef float    f32x4 __attribute__((ext_vector_type(4)));

constexpr int kBT = 1024, kD1 = 256, kD2 = 128, kDM = 1024, kV = 32000, kK = 4;
constexpr int AR = kBT * kK;                    // 4096 rows of (bt,k)
constexpr int ROWS_H = kK * kDM;                // 4096
constexpr int ROWS_U = kK * kD2;                // 512
constexpr int ROWS_ALL = ROWS_H + ROWS_U + kK;  // 4612
constexpr int SLICES = 8;
constexpr int SLICE_ROWS = (ROWS_ALL + SLICES - 1) / SLICES;  // 577
constexpr int NBY = kV / 128;                   // 250 v-panels

constexpr int PREP_BLOCKS = (kBT / 8) * SLICES;        // 1024
constexpr int CVTV_BLOCKS = (kV * kD2 / 8) / 256;      // 2000
constexpr int CVTE_BLOCKS = (kV * kDM / 8) / 256;      // 16000

// ---------------------------------------------------------------------------
// prep_cvt: ONE dispatch doing prep-GEMM (1024 blocks), vmat cvt (2000),
// emb cvt (16000). Overlaps compute-bound prep with BW-bound cvts and saves
// two launch overheads.
// ---------------------------------------------------------------------------
__global__ __launch_bounds__(256) void prep_cvt(
    const float* __restrict__ gc, const float* __restrict__ Hm,
    const float* __restrict__ Um, const float* __restrict__ um,
    const float* __restrict__ vmat, const float* __restrict__ emb,
    f16* __restrict__ hc, f16* __restrict__ tu, float* __restrict__ ug,
    f16* __restrict__ v16, f16* __restrict__ e16)
{
    __shared__ float sgc[8][kD1];
    const int bid = blockIdx.x;

    if (bid >= PREP_BLOCKS) {
        // ---- cvt branch: fp32 -> fp16, 8 elems/thread ----
        const float* src;
        f16* dst;
        int i;
        if (bid < PREP_BLOCKS + CVTV_BLOCKS) {
            src = vmat; dst = v16;
            i = (bid - PREP_BLOCKS) * 256 + threadIdx.x;
        } else {
            src = emb; dst = e16;
            i = (bid - PREP_BLOCKS - CVTV_BLOCKS) * 256 + threadIdx.x;
        }
        const float4 x0 = *reinterpret_cast<const float4*>(src + (size_t)i * 8);
        const float4 x1 = *reinterpret_cast<const float4*>(src + (size_t)i * 8 + 4);
        union { f16 h[8]; uint4 v; } u;
        u.h[0] = (f16)x0.x; u.h[1] = (f16)x0.y; u.h[2] = (f16)x0.z; u.h[3] = (f16)x0.w;
        u.h[4] = (f16)x1.x; u.h[5] = (f16)x1.y; u.h[6] = (f16)x1.z; u.h[7] = (f16)x1.w;
        *reinterpret_cast<uint4*>(dst + (size_t)i * 8) = u.v;
        return;
    }

    // ---- prep branch: grid (128 x 8) flattened ----
    const int pbx = bid & 127;          // bt-group
    const int pby = bid >> 7;           // row slice
    const int btBase = pbx * 8;
    for (int idx = threadIdx.x; idx < 8 * kD1; idx += 256)
        sgc[idx / kD1][idx % kD1] = gc[(size_t)btBase * kD1 + idx];
    __syncthreads();

    const int rStart = pby * SLICE_ROWS;
    int rEnd = rStart + SLICE_ROWS;
    if (rEnd > ROWS_ALL) rEnd = ROWS_ALL;
    for (int r = rStart + (int)threadIdx.x; r < rEnd; r += 256) {
        const float* wrow;
        if (r < ROWS_H)               wrow = Hm + (size_t)r * kD1;
        else if (r < ROWS_H + ROWS_U) wrow = Um + (size_t)(r - ROWS_H) * kD1;
        else                          wrow = um + (size_t)(r - ROWS_H - ROWS_U) * kD1;

        float acc[8] = {0.f,0.f,0.f,0.f,0.f,0.f,0.f,0.f};
        for (int i = 0; i < kD1; i += 4) {
            const float4 w = *reinterpret_cast<const float4*>(wrow + i);
            #pragma unroll
            for (int b = 0; b < 8; ++b) {
                const float4 g = *reinterpret_cast<const float4*>(&sgc[b][i]);
                acc[b] = fmaf(w.x, g.x, acc[b]);
                acc[b] = fmaf(w.y, g.y, acc[b]);
                acc[b] = fmaf(w.z, g.z, acc[b]);
                acc[b] = fmaf(w.w, g.w, acc[b]);
            }
        }
        #pragma unroll
        for (int b = 0; b < 8; ++b) {
            const int bt = btBase + b;
            if (r < ROWS_H) {
                const int k = r >> 10, d = r & 1023;
                hc[((size_t)(bt * kK + k) << 10) + d] = (f16)tanhf(acc[b]);
            } else if (r < ROWS_H + ROWS_U) {
                const int r2 = r - ROWS_H;
                const int k = r2 >> 7, j = r2 & 127;
                tu[(size_t)(bt * kK + k) * kD2 + j] = (f16)tanhf(acc[b]);
            } else {
                ug[bt * kK + (r - ROWS_H - ROWS_U)] = acc[b];
            }
        }
    }
}

__device__ __forceinline__ uint packf16x2(float a, float b) {
    union { f16 h[2]; uint u; } z;
    z.h[0] = (f16)a; z.h[1] = (f16)b;
    return z.u;
}

// ---------------------------------------------------------------------------
// fused_mfma: gate GEMM (4 tiles, D2) + dots GEMM (32 tiles, DM), BK=32.
// vs round 16 (proven 397us): BK 64->32 halves LDS to 2x16KB = 32 KiB
// -> 4-5 blocks/CU (16-20 waves/CU, was 8). Diagnosis: MfmaUtil 34% +
// LDS-BW 41% + HBM 13% + Occupancy 22% = latency-bound; per-MAC traffic
// unchanged, only latency hiding improves.
// LDS rows = 32 f16 = 4x16B slots; swizzle = round-7 PROVEN (0 conflicts):
// read phys slot = fq^((fr>>1)&3); staging dest linear, global col
// pre-swizzled ((l&3)^((l>>3)&3))*8; gload_lds offset imm ALWAYS 0.
// Ledger (same proof as r13/14): per tile T: stage(T+1) [4 loads];
// vmcnt(4) [retires T's 4]; bar; 8 ds_read + 16 MFMA (setprio); bar.
// WAR: stage(T+1) writes buf (T+1)&1, last read tile T-1, completed
// before bar2(T-1) which precedes stage(T+1). Tail vmcnt(0).
// Epilogue: fp16 logits + per-(bt,block) exp-sums (round-16 proven).
// ---------------------------------------------------------------------------
__global__ __launch_bounds__(256) void fused_mfma(
    const f16* __restrict__ hc,  const f16* __restrict__ tu,
    const f16* __restrict__ v16, const f16* __restrict__ e16,
    const float* __restrict__ ug, const float* __restrict__ bmat,
    f16* __restrict__ lg16, float* __restrict__ psum)
{
    __shared__ __align__(16) f16 sA[2][128 * 32];   // 16 KiB
    __shared__ __align__(16) f16 sB[2][128 * 32];   // 16 KiB

    const int tid  = threadIdx.x;
    const int lane = tid & 63;
    const int wave = tid >> 6;
    const int fr = lane & 15, fq = lane >> 4;
    const int wrow = wave >> 1, wcol = wave & 1;
    const int aRowBase = blockIdx.x * 128;
    const int vBase    = blockIdx.y * 128;
    const int btB      = blockIdx.x * 32 + wrow * 16;

    // staging: chunk = 16 rows x 64B; lane l -> row l>>2, phys slot l&3,
    // global col inverse-swizzled so logical slot = (l&3)^((l>>3)&3).
    const int srow = lane >> 2;                               // 0..15
    const int scol = ((lane & 3) ^ ((lane >> 3) & 3)) * 8;    // f16 units

    // per-thread bases; wave w stages A rows w*32..w*32+31 (2 chunks) + B same.
    const f16* gApt = tu  + (size_t)(aRowBase + wave * 32 + srow) * kD2 + scol;
    const f16* gBpt = v16 + (size_t)(vBase    + wave * 32 + srow) * kD2 + scol;
    const f16* sApt = hc  + (size_t)(aRowBase + wave * 32 + srow) * kDM + scol;
    const f16* sBpt = e16 + (size_t)(vBase    + wave * 32 + srow) * kDM + scol;

    f16* dA = &sA[0][0] + wave * 2 * 512;   // + buf*4096 + i*512
    f16* dB = &sB[0][0] + wave * 2 * 512;

#define GLD(SRC, DST)                                                         \
    __builtin_amdgcn_global_load_lds(                                         \
        (const __attribute__((address_space(1))) void*)(SRC),                 \
        (__attribute__((address_space(3))) void*)(DST), 16, 0, 0)

    auto stage_gate = [&](int t) {          // t = 0..3 literal -> buf t&1
        #pragma unroll
        for (int i = 0; i < 2; ++i) {
            GLD(gApt + t * 32 + i * 16 * kD2, dA + (t & 1) * 4096 + i * 512);
            GLD(gBpt + t * 32 + i * 16 * kD2, dB + (t & 1) * 4096 + i * 512);
        }
    };
    auto stage_dots = [&](int buf) {        // running pointers, +32/tile
        #pragma unroll
        for (int i = 0; i < 2; ++i) {
            GLD(sApt + i * 16 * kDM, dA + buf * 4096 + i * 512);
            GLD(sBpt + i * 16 * kDM, dB + buf * 4096 + i * 512);
        }
        sApt += 32; sBpt += 32;
    };

    // lane-constant read bases: phys slot = fq^((fr>>1)&3); row term fr
    // only ((wrow*64 + m*16)>>1 ≡ 0 mod 4).
    const int ps = (fq ^ ((fr >> 1) & 3)) * 8;
    const f16* rA = &sA[0][0] + (wrow * 64 + fr) * 32 + ps;
    const f16* rB = &sB[0][0] + (wcol * 64 + fr) * 32 + ps;

    auto mmStep = [&](f32x4 (&acc)[4][4], int q) {
        const int qo = q * 4096;
        f16x8 b[4];
        #pragma unroll
        for (int n = 0; n < 4; ++n)
            b[n] = *reinterpret_cast<const f16x8*>(rB + qo + n * 512);
        __builtin_amdgcn_s_setprio(1);
        #pragma unroll
        for (int m = 0; m < 4; ++m) {
            const f16x8 a = *reinterpret_cast<const f16x8*>(rA + qo + m * 512);
            #pragma unroll
            for (int n = 0; n < 4; ++n)
                acc[m][n] = __builtin_amdgcn_mfma_f32_16x16x32_f16(
                    a, b[n], acc[m][n], 0, 0, 0);
        }
        __builtin_amdgcn_s_setprio(0);
    };

#define WAITBAR                                                               \
    asm volatile("s_waitcnt vmcnt(4)" ::: "memory");                          \
    __builtin_amdgcn_s_barrier();                                             \
    asm volatile("" ::: "memory");
#define ENDBAR                                                                \
    asm volatile("" ::: "memory");                                            \
    __builtin_amdgcn_s_barrier();                                             \
    asm volatile("" ::: "memory");

    const f32x4 zz = {0.f, 0.f, 0.f, 0.f};

    // ---------------- gate phase: 4 BK32 tiles over D2 ----------------
    f32x4 gacc[4][4];
    #pragma unroll
    for (int m = 0; m < 4; ++m)
        #pragma unroll
        for (int n = 0; n < 4; ++n) gacc[m][n] = zz;

    stage_gate(0);
    stage_gate(1);      WAITBAR  mmStep(gacc, 0);  ENDBAR
    stage_gate(2);      WAITBAR  mmStep(gacc, 1);  ENDBAR
    stage_gate(3);      WAITBAR  mmStep(gacc, 0);  ENDBAR
    stage_dots(0);      WAITBAR  mmStep(gacc, 1);  ENDBAR

    // ---------------- pi conversion (registers only) ----------------
    uint pi01[4][4], pi23[4][4];
    {
        float4 bb[4];
        #pragma unroll
        for (int n = 0; n < 4; ++n)
            bb[n] = *reinterpret_cast<const float4*>(
                bmat + (size_t)(vBase + wcol * 64 + n * 16 + fr) * 4);
        #pragma unroll
        for (int m = 0; m < 4; ++m) {
            const float4 ugv = *reinterpret_cast<const float4*>(
                ug + (btB + m * 4 + fq) * 4);
            #pragma unroll
            for (int n = 0; n < 4; ++n) {
                const float l0 = gacc[m][n][0] + ugv.x + bb[n].x;
                const float l1 = gacc[m][n][1] + ugv.y + bb[n].y;
                const float l2 = gacc[m][n][2] + ugv.z + bb[n].z;
                const float g0 = 1.f / (1.f + __expf(-l0));
                const float g1 = 1.f / (1.f + __expf(-l1));
                const float g2 = 1.f / (1.f + __expf(-l2));
                pi01[m][n] = packf16x2(g0 * g1, g0 * (1.f - g1));
                pi23[m][n] = packf16x2((1.f - g0) * g2, (1.f - g0) * (1.f - g2));
            }
        }
    }

    // ---------------- dots phase: 32 BK32 tiles over DM ----------------
    f32x4 dacc[4][4];
    #pragma unroll
    for (int m = 0; m < 4; ++m)
        #pragma unroll
        for (int n = 0; n < 4; ++n) dacc[m][n] = zz;

    for (int it = 0; it < 15; ++it) {
        stage_dots(1);  WAITBAR  mmStep(dacc, 0);  ENDBAR
        stage_dots(0);  WAITBAR  mmStep(dacc, 1);  ENDBAR
    }
    stage_dots(1);      WAITBAR  mmStep(dacc, 0);  ENDBAR
    asm volatile("s_waitcnt vmcnt(0)" ::: "memory");
    __builtin_amdgcn_s_barrier();
    asm volatile("" ::: "memory");
    mmStep(dacc, 1);
#undef WAITBAR
#undef ENDBAR
#undef GLD

    // -------- epilogue: fp16 logits + exp partial sums (consistent) --------
    #pragma unroll
    for (int m = 0; m < 4; ++m) {
        const int bt = btB + m * 4 + fq;
        float es = 0.f;
        #pragma unroll
        for (int n = 0; n < 4; ++n) {
            const int v = vBase + wcol * 64 + n * 16 + fr;
            union { uint u; f16 h[2]; } p01, p23;
            p01.u = pi01[m][n]; p23.u = pi23[m][n];
            const float lg = (float)p01.h[0] * dacc[m][n][0]
                           + (float)p01.h[1] * dacc[m][n][1]
                           + (float)p23.h[0] * dacc[m][n][2]
                           + (float)p23.h[1] * dacc[m][n][3];
            const f16 lh = (f16)lg;
            lg16[(size_t)bt * kV + v] = lh;
            es += __expf((float)lh);
        }
        es += __shfl_xor(es, 1);
        es += __shfl_xor(es, 2);
        es += __shfl_xor(es, 4);
        es += __shfl_xor(es, 8);
        if (fr == 0)
            psum[(size_t)bt * 512 + blockIdx.y * 2 + wcol] = es;
    }
}

// ---------------------------------------------------------------------------
// softmax scale pass: denom from psum partials; reads fp16 logits,
// writes fp32 probs.
// ---------------------------------------------------------------------------
__global__ __launch_bounds__(256) void softmax_kernel(
    float* __restrict__ out, const f16* __restrict__ lg16,
    const float* __restrict__ psum)
{
    __shared__ float red[4];
    const int bt = blockIdx.x;
    const f16* row16 = lg16 + (size_t)bt * kV;
    float* row = out + (size_t)bt * kV;
    const int tid = threadIdx.x;

    float s = 0.f;
    for (int i = tid; i < 2 * NBY; i += 256) s += psum[(size_t)bt * 512 + i];
    #pragma unroll
    for (int o = 1; o < 64; o <<= 1) s += __shfl_xor(s, o);
    if ((tid & 63) == 0) red[tid >> 6] = s;
    __syncthreads();
    s = red[0] + red[1] + red[2] + red[3];
    const float inv = 1.f / s;

    for (int i = tid * 8; i < kV; i += 2048) {
        union { uint4 v; f16 h[8]; } u;
        u.v = *reinterpret_cast<const uint4*>(row16 + i);
        float4 y0, y1;
        y0.x = __expf((float)u.h[0]) * inv;
        y0.y = __expf((float)u.h[1]) * inv;
        y0.z = __expf((float)u.h[2]) * inv;
        y0.w = __expf((float)u.h[3]) * inv;
        y1.x = __expf((float)u.h[4]) * inv;
        y1.y = __expf((float)u.h[5]) * inv;
        y1.z = __expf((float)u.h[6]) * inv;
        y1.w = __expf((float)u.h[7]) * inv;
        *reinterpret_cast<float4*>(row + i)     = y0;
        *reinterpret_cast<float4*>(row + i + 4) = y1;
    }
}

} // namespace

extern "C" void kernel_launch(void* const* d_in, const int* in_sizes, int n_in,
                              void* d_out, int out_size, void* d_ws, size_t ws_size,
                              hipStream_t stream)
{
    (void)in_sizes; (void)n_in; (void)out_size; (void)ws_size;
    const float* gc   = (const float*)d_in[0];
    const float* Hm   = (const float*)d_in[1];
    const float* Um   = (const float*)d_in[2];
    const float* vmat = (const float*)d_in[3];
    const float* um   = (const float*)d_in[4];
    const float* bmat = (const float*)d_in[5];
    const float* emb  = (const float*)d_in[6];
    float* out = (float*)d_out;

    size_t off = 0;
    auto take = [&](size_t bytes) -> char* {
        char* p = (char*)d_ws + off;
        off += (bytes + 255) & ~(size_t)255;
        return p;
    };
    f16*   hc   = (f16*)  take((size_t)AR * kDM * 2);   //  8 MB
    f16*   tu   = (f16*)  take((size_t)AR * kD2 * 2);   //  1 MB
    f16*   v16  = (f16*)  take((size_t)kV * kD2 * 2);   //  8 MB
    f16*   e16  = (f16*)  take((size_t)kV * kDM * 2);   // 64 MB
    float* ug   = (float*)take((size_t)AR * 4);
    float* psum = (float*)take((size_t)kBT * 512 * 4);  //  2 MB
    f16*   lg16 = (f16*)  take((size_t)kBT * kV * 2);   // 64 MB

    prep_cvt<<<dim3(PREP_BLOCKS + CVTV_BLOCKS + CVTE_BLOCKS), 256, 0, stream>>>(
        gc, Hm, Um, um, vmat, emb, hc, tu, ug, v16, e16);
    fused_mfma<<<dim3(AR / 128, NBY), 256, 0, stream>>>(
        hc, tu, v16, e16, ug, bmat, lg16, psum);
    softmax_kernel<<<dim3(kBT), 256, 0, stream>>>(out, lg16, psum);
}

// Round 18
// 517.755 us; speedup vs baseline: 1.1764x; 1.1764x over previous
//
#include <hip/hip_runtime.h>
#include <math.h>

namespace {

typedef _Float16 f16;
typedef _Float16 f16x8 __attribute__((ext_vector_type(8)));
typedef float    f32x4 __attribute__((ext_vector_type(4)));

constexpr int kBT = 1024, kD1 = 256, kD2 = 128, kDM = 1024, kV = 32000, kK = 4;
constexpr int AR = kBT * kK;                    // 4096 rows of (bt,k)
constexpr int ROWS_H = kK * kDM;                // 4096
constexpr int ROWS_U = kK * kD2;                // 512
constexpr int ROWS_ALL = ROWS_H + ROWS_U + kK;  // 4612
constexpr int SLICES = 8;
constexpr int SLICE_ROWS = (ROWS_ALL + SLICES - 1) / SLICES;  // 577
constexpr int NBY = kV / 128;                   // 250 v-panels

constexpr int PREP_BLOCKS = (kBT / 8) * SLICES;        // 1024
constexpr int CVTV_BLOCKS = (kV * kD2 / 8) / 256;      // 2000
constexpr int CVTE_BLOCKS = (kV * kDM / 8) / 256;      // 16000

// ---------------------------------------------------------------------------
// prep_cvt: ONE dispatch doing prep-GEMM (1024 blocks), vmat cvt (2000),
// emb cvt (16000). Proven in round 17 (~25-30us vs separate launches).
// ---------------------------------------------------------------------------
__global__ __launch_bounds__(256) void prep_cvt(
    const float* __restrict__ gc, const float* __restrict__ Hm,
    const float* __restrict__ Um, const float* __restrict__ um,
    const float* __restrict__ vmat, const float* __restrict__ emb,
    f16* __restrict__ hc, f16* __restrict__ tu, float* __restrict__ ug,
    f16* __restrict__ v16, f16* __restrict__ e16)
{
    __shared__ float sgc[8][kD1];
    const int bid = blockIdx.x;

    if (bid >= PREP_BLOCKS) {
        // ---- cvt branch: fp32 -> fp16, 8 elems/thread ----
        const float* src;
        f16* dst;
        int i;
        if (bid < PREP_BLOCKS + CVTV_BLOCKS) {
            src = vmat; dst = v16;
            i = (bid - PREP_BLOCKS) * 256 + threadIdx.x;
        } else {
            src = emb; dst = e16;
            i = (bid - PREP_BLOCKS - CVTV_BLOCKS) * 256 + threadIdx.x;
        }
        const float4 x0 = *reinterpret_cast<const float4*>(src + (size_t)i * 8);
        const float4 x1 = *reinterpret_cast<const float4*>(src + (size_t)i * 8 + 4);
        union { f16 h[8]; uint4 v; } u;
        u.h[0] = (f16)x0.x; u.h[1] = (f16)x0.y; u.h[2] = (f16)x0.z; u.h[3] = (f16)x0.w;
        u.h[4] = (f16)x1.x; u.h[5] = (f16)x1.y; u.h[6] = (f16)x1.z; u.h[7] = (f16)x1.w;
        *reinterpret_cast<uint4*>(dst + (size_t)i * 8) = u.v;
        return;
    }

    // ---- prep branch: grid (128 x 8) flattened ----
    const int pbx = bid & 127;          // bt-group
    const int pby = bid >> 7;           // row slice
    const int btBase = pbx * 8;
    for (int idx = threadIdx.x; idx < 8 * kD1; idx += 256)
        sgc[idx / kD1][idx % kD1] = gc[(size_t)btBase * kD1 + idx];
    __syncthreads();

    const int rStart = pby * SLICE_ROWS;
    int rEnd = rStart + SLICE_ROWS;
    if (rEnd > ROWS_ALL) rEnd = ROWS_ALL;
    for (int r = rStart + (int)threadIdx.x; r < rEnd; r += 256) {
        const float* wrow;
        if (r < ROWS_H)               wrow = Hm + (size_t)r * kD1;
        else if (r < ROWS_H + ROWS_U) wrow = Um + (size_t)(r - ROWS_H) * kD1;
        else                          wrow = um + (size_t)(r - ROWS_H - ROWS_U) * kD1;

        float acc[8] = {0.f,0.f,0.f,0.f,0.f,0.f,0.f,0.f};
        for (int i = 0; i < kD1; i += 4) {
            const float4 w = *reinterpret_cast<const float4*>(wrow + i);
            #pragma unroll
            for (int b = 0; b < 8; ++b) {
                const float4 g = *reinterpret_cast<const float4*>(&sgc[b][i]);
                acc[b] = fmaf(w.x, g.x, acc[b]);
                acc[b] = fmaf(w.y, g.y, acc[b]);
                acc[b] = fmaf(w.z, g.z, acc[b]);
                acc[b] = fmaf(w.w, g.w, acc[b]);
            }
        }
        #pragma unroll
        for (int b = 0; b < 8; ++b) {
            const int bt = btBase + b;
            if (r < ROWS_H) {
                const int k = r >> 10, d = r & 1023;
                hc[((size_t)(bt * kK + k) << 10) + d] = (f16)tanhf(acc[b]);
            } else if (r < ROWS_H + ROWS_U) {
                const int r2 = r - ROWS_H;
                const int k = r2 >> 7, j = r2 & 127;
                tu[(size_t)(bt * kK + k) * kD2 + j] = (f16)tanhf(acc[b]);
            } else {
                ug[bt * kK + (r - ROWS_H - ROWS_U)] = acc[b];
            }
        }
    }
}

__device__ __forceinline__ uint packf16x2(float a, float b) {
    union { f16 h[2]; uint u; } z;
    z.h[0] = (f16)a; z.h[1] = (f16)b;
    return z.u;
}

// ---------------------------------------------------------------------------
// fused_mfma: gate GEMM (K=128, 2 tiles) + dots GEMM (K=1024, 16 tiles).
// ROUND-16 PROVEN KERNEL (397us, 108 VGPR, 0 conflicts): 128x128 tile,
// BK=64, 4 waves (2x2), dbuf LDS 64 KiB, XOR-swizzled global_load_lds
// staging (offset imm 0, col in pointer), vmcnt(8) + raw s_barrier,
// lane-constant read bases, setprio around MFMA clusters, running dots
// pointers, fp16-logits + psum epilogue.
// Round-17's BK=32 REVERTED: occupancy stayed 22% (not LDS-capped) while
// barrier/staging overhead per MFMA doubled (-30%).
// ---------------------------------------------------------------------------
__global__ __launch_bounds__(256, 2) void fused_mfma(
    const f16* __restrict__ hc,  const f16* __restrict__ tu,
    const f16* __restrict__ v16, const f16* __restrict__ e16,
    const float* __restrict__ ug, const float* __restrict__ bmat,
    f16* __restrict__ lg16, float* __restrict__ psum)
{
    __shared__ __align__(16) f16 sA[2][128 * 64];   // 32 KiB
    __shared__ __align__(16) f16 sB[2][128 * 64];   // 32 KiB

    const int tid  = threadIdx.x;
    const int lane = tid & 63;
    const int wave = tid >> 6;
    const int fr = lane & 15, fq = lane >> 4;
    const int wrow = wave >> 1, wcol = wave & 1;
    const int aRowBase = blockIdx.x * 128;
    const int vBase    = blockIdx.y * 128;
    const int btB      = blockIdx.x * 32 + wrow * 16;

    // staging geometry: chunk c = wave*4+i covers rows wave*32+i*8 .. +8;
    // lane l -> row srow = l>>3, phys slot l&7 holds logical (l&7)^srow.
    const int srow = lane >> 3;
    const int scol = ((lane & 7) ^ srow) * 8;   // inverse-swizzled global col

    // per-thread staging bases; dots pointers advance +64 per staged tile.
    const f16* gApt = tu  + (size_t)(aRowBase + wave * 32 + srow) * kD2 + scol;
    const f16* gBpt = v16 + (size_t)(vBase    + wave * 32 + srow) * kD2 + scol;
    const f16* sApt = hc  + (size_t)(aRowBase + wave * 32 + srow) * kDM + scol;
    const f16* sBpt = e16 + (size_t)(vBase    + wave * 32 + srow) * kDM + scol;

    f16* dA = &sA[0][0] + wave * 4 * 512;   // + buf*8192 + i*512
    f16* dB = &sB[0][0] + wave * 4 * 512;

#define GLD(SRC, DST)                                                         \
    __builtin_amdgcn_global_load_lds(                                         \
        (const __attribute__((address_space(1))) void*)(SRC),                 \
        (__attribute__((address_space(3))) void*)(DST), 16, 0, 0)

    // gate tile t (t = 0,1 literal) -> buf t.
    auto stage_gate = [&](int t) {
        #pragma unroll
        for (int i = 0; i < 4; ++i) {
            GLD(gApt + t * 64 + i * 8 * kD2, dA + t * 8192 + i * 512);
            GLD(gBpt + t * 64 + i * 8 * kD2, dB + t * 8192 + i * 512);
        }
    };
    // dots tile (running pointers) -> buf.
    auto stage_dots = [&](int buf) {
        #pragma unroll
        for (int i = 0; i < 4; ++i) {
            GLD(sApt + i * 8 * kDM, dA + buf * 8192 + i * 512);
            GLD(sBpt + i * 8 * kDM, dB + buf * 8192 + i * 512);
        }
        sApt += 64; sBpt += 64;
    };

    // lane-constant read bases: ps(kk) = (kk*4+fq)^(fr&7).
    const int ps0 = (fq ^ (fr & 7)) * 8;
    const int ps1 = ((4 + fq) ^ (fr & 7)) * 8;
    const f16* rA0 = &sA[0][0] + (wrow * 64 + fr) * 64 + ps0;
    const f16* rA1 = &sA[0][0] + (wrow * 64 + fr) * 64 + ps1;
    const f16* rB0 = &sB[0][0] + (wcol * 64 + fr) * 64 + ps0;
    const f16* rB1 = &sB[0][0] + (wcol * 64 + fr) * 64 + ps1;

    auto mmStep = [&](f32x4 (&acc)[4][4], int q) {
        const int qo = q * 8192;
        {
            f16x8 a[4], b[4];
            #pragma unroll
            for (int m = 0; m < 4; ++m)
                a[m] = *reinterpret_cast<const f16x8*>(rA0 + qo + m * 1024);
            #pragma unroll
            for (int n = 0; n < 4; ++n)
                b[n] = *reinterpret_cast<const f16x8*>(rB0 + qo + n * 1024);
            __builtin_amdgcn_s_setprio(1);
            #pragma unroll
            for (int m = 0; m < 4; ++m)
                #pragma unroll
                for (int n = 0; n < 4; ++n)
                    acc[m][n] = __builtin_amdgcn_mfma_f32_16x16x32_f16(
                        a[m], b[n], acc[m][n], 0, 0, 0);
            __builtin_amdgcn_s_setprio(0);
        }
        {
            f16x8 a[4], b[4];
            #pragma unroll
            for (int m = 0; m < 4; ++m)
                a[m] = *reinterpret_cast<const f16x8*>(rA1 + qo + m * 1024);
            #pragma unroll
            for (int n = 0; n < 4; ++n)
                b[n] = *reinterpret_cast<const f16x8*>(rB1 + qo + n * 1024);
            __builtin_amdgcn_s_setprio(1);
            #pragma unroll
            for (int m = 0; m < 4; ++m)
                #pragma unroll
                for (int n = 0; n < 4; ++n)
                    acc[m][n] = __builtin_amdgcn_mfma_f32_16x16x32_f16(
                        a[m], b[n], acc[m][n], 0, 0, 0);
            __builtin_amdgcn_s_setprio(0);
        }
    };

#define WAITBAR(VM)                                                           \
    asm volatile("s_waitcnt vmcnt(" VM ")" ::: "memory");                     \
    __builtin_amdgcn_s_barrier();                                             \
    asm volatile("" ::: "memory");
#define ENDBAR                                                                \
    asm volatile("" ::: "memory");                                            \
    __builtin_amdgcn_s_barrier();                                             \
    asm volatile("" ::: "memory");

    const f32x4 zz = {0.f, 0.f, 0.f, 0.f};

    // ---------------- gate phase: tiles 0,1 over D2 ----------------
    f32x4 gacc[4][4];
    #pragma unroll
    for (int m = 0; m < 4; ++m)
        #pragma unroll
        for (int n = 0; n < 4; ++n) gacc[m][n] = zz;

    stage_gate(0);
    stage_gate(1);          WAITBAR("8")  mmStep(gacc, 0);  ENDBAR
    stage_dots(0);          WAITBAR("8")  mmStep(gacc, 1);  ENDBAR

    // ---------------- pi conversion (registers only) ----------------
    uint pi01[4][4], pi23[4][4];
    {
        float4 bb[4];
        #pragma unroll
        for (int n = 0; n < 4; ++n)
            bb[n] = *reinterpret_cast<const float4*>(
                bmat + (size_t)(vBase + wcol * 64 + n * 16 + fr) * 4);
        #pragma unroll
        for (int m = 0; m < 4; ++m) {
            const float4 ugv = *reinterpret_cast<const float4*>(
                ug + (btB + m * 4 + fq) * 4);
            #pragma unroll
            for (int n = 0; n < 4; ++n) {
                const float l0 = gacc[m][n][0] + ugv.x + bb[n].x;
                const float l1 = gacc[m][n][1] + ugv.y + bb[n].y;
                const float l2 = gacc[m][n][2] + ugv.z + bb[n].z;
                const float g0 = 1.f / (1.f + __expf(-l0));
                const float g1 = 1.f / (1.f + __expf(-l1));
                const float g2 = 1.f / (1.f + __expf(-l2));
                pi01[m][n] = packf16x2(g0 * g1, g0 * (1.f - g1));
                pi23[m][n] = packf16x2((1.f - g0) * g2, (1.f - g0) * (1.f - g2));
            }
        }
    }

    // ---------------- dots phase: 16 tiles over DM ----------------
    f32x4 dacc[4][4];
    #pragma unroll
    for (int m = 0; m < 4; ++m)
        #pragma unroll
        for (int n = 0; n < 4; ++n) dacc[m][n] = zz;

    for (int it = 0; it < 7; ++it) {
        stage_dots(1);      WAITBAR("8")  mmStep(dacc, 0);  ENDBAR
        stage_dots(0);      WAITBAR("8")  mmStep(dacc, 1);  ENDBAR
    }
    stage_dots(1);          WAITBAR("8")  mmStep(dacc, 0);  ENDBAR
                            WAITBAR("0")  mmStep(dacc, 1);
#undef WAITBAR
#undef ENDBAR
#undef GLD

    // -------- epilogue: fp16 logits + exp partial sums (consistent) --------
    #pragma unroll
    for (int m = 0; m < 4; ++m) {
        const int bt = btB + m * 4 + fq;
        float es = 0.f;
        #pragma unroll
        for (int n = 0; n < 4; ++n) {
            const int v = vBase + wcol * 64 + n * 16 + fr;
            union { uint u; f16 h[2]; } p01, p23;
            p01.u = pi01[m][n]; p23.u = pi23[m][n];
            const float lg = (float)p01.h[0] * dacc[m][n][0]
                           + (float)p01.h[1] * dacc[m][n][1]
                           + (float)p23.h[0] * dacc[m][n][2]
                           + (float)p23.h[1] * dacc[m][n][3];
            const f16 lh = (f16)lg;                 // round once...
            lg16[(size_t)bt * kV + v] = lh;
            es += __expf((float)lh);                // ...sum the rounded value
        }
        es += __shfl_xor(es, 1);
        es += __shfl_xor(es, 2);
        es += __shfl_xor(es, 4);
        es += __shfl_xor(es, 8);
        if (fr == 0)
            psum[(size_t)bt * 512 + blockIdx.y * 2 + wcol] = es;
    }
}

// ---------------------------------------------------------------------------
// softmax scale pass: denom from psum partials; reads fp16 logits (65MB),
// writes fp32 probs (131MB).
// ---------------------------------------------------------------------------
__global__ __launch_bounds__(256) void softmax_kernel(
    float* __restrict__ out, const f16* __restrict__ lg16,
    const float* __restrict__ psum)
{
    __shared__ float red[4];
    const int bt = blockIdx.x;
    const f16* row16 = lg16 + (size_t)bt * kV;
    float* row = out + (size_t)bt * kV;
    const int tid = threadIdx.x;

    float s = 0.f;
    for (int i = tid; i < 2 * NBY; i += 256) s += psum[(size_t)bt * 512 + i];
    #pragma unroll
    for (int o = 1; o < 64; o <<= 1) s += __shfl_xor(s, o);
    if ((tid & 63) == 0) red[tid >> 6] = s;
    __syncthreads();
    s = red[0] + red[1] + red[2] + red[3];
    const float inv = 1.f / s;

    for (int i = tid * 8; i < kV; i += 2048) {
        union { uint4 v; f16 h[8]; } u;
        u.v = *reinterpret_cast<const uint4*>(row16 + i);
        float4 y0, y1;
        y0.x = __expf((float)u.h[0]) * inv;
        y0.y = __expf((float)u.h[1]) * inv;
        y0.z = __expf((float)u.h[2]) * inv;
        y0.w = __expf((float)u.h[3]) * inv;
        y1.x = __expf((float)u.h[4]) * inv;
        y1.y = __expf((float)u.h[5]) * inv;
        y1.z = __expf((float)u.h[6]) * inv;
        y1.w = __expf((float)u.h[7]) * inv;
        *reinterpret_cast<float4*>(row + i)     = y0;
        *reinterpret_cast<float4*>(row + i + 4) = y1;
    }
}

} // namespace

extern "C" void kernel_launch(void* const* d_in, const int* in_sizes, int n_in,
                              void* d_out, int out_size, void* d_ws, size_t ws_size,
                              hipStream_t stream)
{
    (void)in_sizes; (void)n_in; (void)out_size; (void)ws_size;
    const float* gc   = (const float*)d_in[0];
    const float* Hm   = (const float*)d_in[1];
    const float* Um   = (const float*)d_in[2];
    const float* vmat = (const float*)d_in[3];
    const float* um   = (const float*)d_in[4];
    const float* bmat = (const float*)d_in[5];
    const float* emb  = (const float*)d_in[6];
    float* out = (float*)d_out;

    size_t off = 0;
    auto take = [&](size_t bytes) -> char* {
        char* p = (char*)d_ws + off;
        off += (bytes + 255) & ~(size_t)255;
        return p;
    };
    f16*   hc   = (f16*)  take((size_t)AR * kDM * 2);   //  8 MB
    f16*   tu   = (f16*)  take((size_t)AR * kD2 * 2);   //  1 MB
    f16*   v16  = (f16*)  take((size_t)kV * kD2 * 2);   //  8 MB
    f16*   e16  = (f16*)  take((size_t)kV * kDM * 2);   // 64 MB
    float* ug   = (float*)take((size_t)AR * 4);
    float* psum = (float*)take((size_t)kBT * 512 * 4);  //  2 MB
    f16*   lg16 = (f16*)  take((size_t)kBT * kV * 2);   // 64 MB

    prep_cvt<<<dim3(PREP_BLOCKS + CVTV_BLOCKS + CVTE_BLOCKS), 256, 0, stream>>>(
        gc, Hm, Um, um, vmat, emb, hc, tu, ug, v16, e16);
    fused_mfma<<<dim3(AR / 128, NBY), 256, 0, stream>>>(
        hc, tu, v16, e16, ug, bmat, lg16, psum);
    softmax_kernel<<<dim3(kBT), 256, 0, stream>>>(out, lg16, psum);
}